// Round 1
// baseline (615.256 us; speedup 1.0000x reference)
//
#include <hip/hip_runtime.h>

typedef __bf16 bf16x8 __attribute__((ext_vector_type(8)));
typedef float f32x4 __attribute__((ext_vector_type(4)));
typedef unsigned short u16x8 __attribute__((ext_vector_type(8)));
typedef unsigned short u16x4 __attribute__((ext_vector_type(4)));
typedef unsigned int __attribute__((address_space(1))) as1_uint;
typedef unsigned int __attribute__((address_space(3))) as3_uint;

#define S_LEN 2048
#define NB 4
#define NH 16
#define HD 64
#define DM 1024

__device__ __forceinline__ unsigned short f2bf(float f) {
  union { float f; unsigned int u; } v; v.f = f;
  unsigned int r = v.u + 0x7fffu + ((v.u >> 16) & 1u);
  return (unsigned short)(r >> 16);
}

// ---------- kernel 1: X fp32 -> bf16 (layout preserved, 8192x1024) ----------
__global__ __launch_bounds__(256) void cvt_x(const float* __restrict__ x,
                                             unsigned short* __restrict__ xb) {
  int i = (blockIdx.x * 256 + threadIdx.x) * 8;
  f32x4 a = *(const f32x4*)(x + i);
  f32x4 b = *(const f32x4*)(x + i + 4);
  u16x8 o;
  o[0] = f2bf(a[0]); o[1] = f2bf(a[1]); o[2] = f2bf(a[2]); o[3] = f2bf(a[3]);
  o[4] = f2bf(b[0]); o[5] = f2bf(b[1]); o[6] = f2bf(b[2]); o[7] = f2bf(b[3]);
  *(u16x8*)(xb + i) = o;
}

// ---------- kernel 2: W (K,N) fp32 -> WT (N,K) bf16, for q/k/v via blockIdx.z ----------
__global__ __launch_bounds__(256) void cvt_wt(const float* __restrict__ Wq,
                                              const float* __restrict__ Wk,
                                              const float* __restrict__ Wv,
                                              unsigned short* __restrict__ wt) {
  const float* W = (blockIdx.z == 0) ? Wq : (blockIdx.z == 1) ? Wk : Wv;
  unsigned short* WT = wt + (size_t)blockIdx.z * DM * DM;
  __shared__ float tile[32][33];
  int tx = threadIdx.x & 31, ty = threadIdx.x >> 5;
  int k0 = blockIdx.x * 32, n0 = blockIdx.y * 32;
#pragma unroll
  for (int i = 0; i < 4; ++i)
    tile[ty + 8 * i][tx] = W[(size_t)(k0 + ty + 8 * i) * DM + n0 + tx];
  __syncthreads();
#pragma unroll
  for (int i = 0; i < 4; ++i)
    WT[(size_t)(n0 + ty + 8 * i) * DM + k0 + tx] = f2bf(tile[tx][ty + 8 * i]);
}

// ---------- kernel 3: QKV GEMM: Y = Xb @ W + b ----------
// z=0 -> Q (B,H,S,HD) bf16 ; z=1 -> K (B,H,S,HD) bf16 ; z=2 -> V^T (B,H,HD,S) bf16
__global__ __launch_bounds__(256) void qkv_gemm(const unsigned short* __restrict__ xb,
                                                const unsigned short* __restrict__ wt,
                                                const float* __restrict__ bq,
                                                const float* __restrict__ bk,
                                                const float* __restrict__ bv,
                                                unsigned short* __restrict__ qo,
                                                unsigned short* __restrict__ ko,
                                                unsigned short* __restrict__ vto) {
  const int z = blockIdx.z;
  const unsigned short* WT = wt + (size_t)z * DM * DM;
  const float* bias = (z == 0) ? bq : (z == 1) ? bk : bv;
  const int m0 = blockIdx.x * 128;
  const int n0 = blockIdx.y * 128;
  __shared__ __align__(16) unsigned short Al[128 * 32];
  __shared__ __align__(16) unsigned short Bl[128 * 32];
  const int tid = threadIdx.x;
  const int wave = tid >> 6, lane = tid & 63, quad = lane >> 4, lw = lane & 15;
  const int wm = (wave >> 1) * 64, wn = (wave & 1) * 64;

  f32x4 acc[4][4];
#pragma unroll
  for (int mt = 0; mt < 4; ++mt)
#pragma unroll
    for (int nt = 0; nt < 4; ++nt) acc[mt][nt] = (f32x4){0.f, 0.f, 0.f, 0.f};

  for (int k0 = 0; k0 < DM; k0 += 32) {
    __syncthreads();
#pragma unroll
    for (int i = 0; i < 2; ++i) {
      int c = i * 256 + tid;
      const unsigned short* ga = xb + (size_t)(m0 + (c >> 2)) * DM + k0 + (c & 3) * 8;
      __builtin_amdgcn_global_load_lds((const as1_uint*)ga, (as3_uint*)(Al + c * 8), 16, 0, 0);
      const unsigned short* gb = WT + (size_t)(n0 + (c >> 2)) * DM + k0 + (c & 3) * 8;
      __builtin_amdgcn_global_load_lds((const as1_uint*)gb, (as3_uint*)(Bl + c * 8), 16, 0, 0);
    }
    __syncthreads();
    bf16x8 af[4], bfr[4];
#pragma unroll
    for (int mt = 0; mt < 4; ++mt)
      af[mt] = *(const bf16x8*)(Al + (wm + mt * 16 + lw) * 32 + quad * 8);
#pragma unroll
    for (int nt = 0; nt < 4; ++nt)
      bfr[nt] = *(const bf16x8*)(Bl + (wn + nt * 16 + lw) * 32 + quad * 8);
#pragma unroll
    for (int mt = 0; mt < 4; ++mt)
#pragma unroll
      for (int nt = 0; nt < 4; ++nt)
        acc[mt][nt] = __builtin_amdgcn_mfma_f32_16x16x32_bf16(af[mt], bfr[nt], acc[mt][nt], 0, 0, 0);
  }

  float bias4[4];
#pragma unroll
  for (int nt = 0; nt < 4; ++nt) bias4[nt] = bias[n0 + wn + nt * 16 + lw];

  if (z < 2) {
    unsigned short* dst = (z == 0) ? qo : ko;
#pragma unroll
    for (int mt = 0; mt < 4; ++mt) {
#pragma unroll
      for (int nt = 0; nt < 4; ++nt) {
        int n = n0 + wn + nt * 16 + lw;
        int h = n >> 6, d = n & 63;
#pragma unroll
        for (int r = 0; r < 4; ++r) {
          int m = m0 + wm + mt * 16 + quad * 4 + r;
          int b = m >> 11, s = m & 2047;
          dst[((size_t)(b * NH + h) * S_LEN + s) * HD + d] = f2bf(acc[mt][nt][r] + bias4[nt]);
        }
      }
    }
  } else {
#pragma unroll
    for (int mt = 0; mt < 4; ++mt) {
#pragma unroll
      for (int nt = 0; nt < 4; ++nt) {
        int n = n0 + wn + nt * 16 + lw;
        int h = n >> 6, d = n & 63;
        int mb = m0 + wm + mt * 16 + quad * 4;
        int b = mb >> 11, s = mb & 2047;
        u16x4 pk;
#pragma unroll
        for (int r = 0; r < 4; ++r) pk[r] = f2bf(acc[mt][nt][r] + bias4[nt]);
        *(u16x4*)(vto + ((size_t)(b * NH + h) * HD + d) * S_LEN + s) = pk;
      }
    }
  }
}

// ---------- kernel 4: causal flash attention ----------
// grid: (S/64, B*H), block 256 (4 waves, 16 q-rows each)
__global__ __launch_bounds__(256) void attn(const unsigned short* __restrict__ Qb,
                                            const unsigned short* __restrict__ Kb,
                                            const unsigned short* __restrict__ Vtb,
                                            float* __restrict__ out) {
  const int bh = blockIdx.y;
  const int b = bh >> 4, h = bh & 15;
  const int wave = threadIdx.x >> 6, lane = threadIdx.x & 63;
  const int quad = lane >> 4, lw = lane & 15;
  const int qw = blockIdx.x * 64 + wave * 16;
  const unsigned short* Qp = Qb + (size_t)bh * S_LEN * HD;
  const unsigned short* Kp = Kb + (size_t)bh * S_LEN * HD;
  const unsigned short* Vp = Vtb + (size_t)bh * HD * S_LEN;

  __shared__ __align__(16) unsigned short P_lds[4][16][72];
  unsigned short(*myP)[72] = P_lds[wave];

  bf16x8 aq0 = *(const bf16x8*)(Qp + (size_t)(qw + lw) * HD + quad * 8);
  bf16x8 aq1 = *(const bf16x8*)(Qp + (size_t)(qw + lw) * HD + 32 + quad * 8);

  f32x4 accO[4];
#pragma unroll
  for (int dg = 0; dg < 4; ++dg) accO[dg] = (f32x4){0.f, 0.f, 0.f, 0.f};
  float m_i[4], l_i[4];
#pragma unroll
  for (int r = 0; r < 4; ++r) { m_i[r] = -1e30f; l_i[r] = 0.f; }

  const float scale = 0.125f;  // 1/sqrt(64)
  const int ntiles = (qw + 16 + 63) >> 6;
  for (int t = 0; t < ntiles; ++t) {
    const int kv = t << 6;
    f32x4 sc[4];
#pragma unroll
    for (int g = 0; g < 4; ++g) sc[g] = (f32x4){0.f, 0.f, 0.f, 0.f};
#pragma unroll
    for (int g = 0; g < 4; ++g) {
      const unsigned short* kr = Kp + (size_t)(kv + g * 16 + lw) * HD + quad * 8;
      sc[g] = __builtin_amdgcn_mfma_f32_16x16x32_bf16(aq0, *(const bf16x8*)kr, sc[g], 0, 0, 0);
      sc[g] = __builtin_amdgcn_mfma_f32_16x16x32_bf16(aq1, *(const bf16x8*)(kr + 32), sc[g], 0, 0, 0);
    }
#pragma unroll
    for (int g = 0; g < 4; ++g)
#pragma unroll
      for (int r = 0; r < 4; ++r) sc[g][r] *= scale;
    if (kv + 63 > qw) {  // diagonal / partially masked tile
#pragma unroll
      for (int g = 0; g < 4; ++g)
#pragma unroll
        for (int r = 0; r < 4; ++r)
          if (kv + g * 16 + lw > qw + quad * 4 + r) sc[g][r] = -1e30f;
    }
    float mloc[4];
#pragma unroll
    for (int r = 0; r < 4; ++r)
      mloc[r] = fmaxf(fmaxf(sc[0][r], sc[1][r]), fmaxf(sc[2][r], sc[3][r]));
#pragma unroll
    for (int off = 1; off < 16; off <<= 1)
#pragma unroll
      for (int r = 0; r < 4; ++r) mloc[r] = fmaxf(mloc[r], __shfl_xor(mloc[r], off, 64));
    float alpha[4];
#pragma unroll
    for (int r = 0; r < 4; ++r) {
      float mn = fmaxf(m_i[r], mloc[r]);
      alpha[r] = __expf(m_i[r] - mn);
      m_i[r] = mn;
    }
    float rsum[4] = {0.f, 0.f, 0.f, 0.f};
#pragma unroll
    for (int g = 0; g < 4; ++g)
#pragma unroll
      for (int r = 0; r < 4; ++r) {
        float p = __expf(sc[g][r] - m_i[r]);
        sc[g][r] = p;
        rsum[r] += p;
      }
#pragma unroll
    for (int off = 1; off < 16; off <<= 1)
#pragma unroll
      for (int r = 0; r < 4; ++r) rsum[r] += __shfl_xor(rsum[r], off, 64);
#pragma unroll
    for (int r = 0; r < 4; ++r) l_i[r] = l_i[r] * alpha[r] + rsum[r];
#pragma unroll
    for (int dg = 0; dg < 4; ++dg)
#pragma unroll
      for (int r = 0; r < 4; ++r) accO[dg][r] *= alpha[r];

    // P: C-layout -> A-layout via per-wave LDS (no barrier; wave-private region)
#pragma unroll
    for (int g = 0; g < 4; ++g)
#pragma unroll
      for (int r = 0; r < 4; ++r) myP[quad * 4 + r][g * 16 + lw] = f2bf(sc[g][r]);
    bf16x8 ap0 = *(const bf16x8*)&myP[lw][quad * 8];
    bf16x8 ap1 = *(const bf16x8*)&myP[lw][32 + quad * 8];
#pragma unroll
    for (int dg = 0; dg < 4; ++dg) {
      const unsigned short* vr = Vp + (size_t)(dg * 16 + lw) * S_LEN + kv + quad * 8;
      accO[dg] = __builtin_amdgcn_mfma_f32_16x16x32_bf16(ap0, *(const bf16x8*)vr, accO[dg], 0, 0, 0);
      accO[dg] = __builtin_amdgcn_mfma_f32_16x16x32_bf16(ap1, *(const bf16x8*)(vr + 32), accO[dg], 0, 0, 0);
    }
  }

  float* op = out + ((size_t)b * S_LEN + qw + quad * 4) * DM + h * HD + lw;
#pragma unroll
  for (int r = 0; r < 4; ++r) {
    float inv = 1.0f / l_i[r];
#pragma unroll
    for (int dg = 0; dg < 4; ++dg) op[(size_t)r * DM + dg * 16] = accO[dg][r] * inv;
  }
}

extern "C" void kernel_launch(void* const* d_in, const int* in_sizes, int n_in,
                              void* d_out, int out_size, void* d_ws, size_t ws_size,
                              hipStream_t stream) {
  const float* x = (const float*)d_in[0];
  const float* Wq = (const float*)d_in[1];
  const float* bq = (const float*)d_in[2];
  const float* Wk = (const float*)d_in[3];
  const float* bk = (const float*)d_in[4];
  const float* Wv = (const float*)d_in[5];
  const float* bv = (const float*)d_in[6];
  float* out = (float*)d_out;

  char* ws = (char*)d_ws;
  unsigned short* xb = (unsigned short*)(ws + 0);          // 16 MB: X bf16 (8192,1024)
  unsigned short* wt = (unsigned short*)(ws + 16777216);   // 6 MB: Wq/Wk/Wv^T bf16
  unsigned short* qb = (unsigned short*)(ws + 23068672);   // 16 MB: Q (B,H,S,64)
  unsigned short* kb = (unsigned short*)(ws + 39845888);   // 16 MB: K (B,H,S,64)
  unsigned short* vt = (unsigned short*)(ws + 56623104);   // 16 MB: V^T (B,H,64,S)

  hipLaunchKernelGGL(cvt_x, dim3(4096), dim3(256), 0, stream, x, xb);
  hipLaunchKernelGGL(cvt_wt, dim3(32, 32, 3), dim3(256), 0, stream, Wq, Wk, Wv, wt);
  hipLaunchKernelGGL(qkv_gemm, dim3(64, 8, 3), dim3(256), 0, stream,
                     xb, wt, bq, bk, bv, qb, kb, vt);
  hipLaunchKernelGGL(attn, dim3(32, 64), dim3(256), 0, stream, qb, kb, vt, out);
}